// Round 8
// baseline (346.524 us; speedup 1.0000x reference)
//
#include <hip/hip_runtime.h>

// SingleLSTM: B=32768, T=28, INPUT=28, HIDDEN=128, LABELS=10, fp32.
// R20 (resubmit; round 7 bench was an infra failure, no data).
// Independent-barrier antiphase. R13..R19 counters are invariant
// (Mfma ~31, VALU ~55, 214us) across ping-pong/SGB/setprio/frag-pipe ->
// the two waves/SIMD are PHASE-LOCKED by their shared block barrier:
// MFMA phase runs lockstep (matrix pipe contended, VALU idle), then act
// phase lockstep (VALU contended, matrix idle). Ledger: MFMA 6.2k cy +
// VALU/trans ~10k cy ~= 16.2k of 18.3k step -> pipes serialized, not
// stalled. Fix: 2 blocks/CU with INDEPENDENT barriers, same 2 waves/
// SIMD: 64 rows/block, 256 thr (4 waves), 512 blocks. Contention drifts
// the blocks into antiphase -> block A's MFMA overlaps block B's act
// (m114: cross-wave MFMA+VALU co-issue ~ max). Wave owns 32 hidden
// cols x 4 gates: Wh[4][8]=128 VGPR (budget 256 at 2 waves/SIMD),
// Wx in LDS (verified R16, zero conflict cost). LDS 75776B/block ->
// exactly 2 blocks/CU (151552 <= 160K).
// Kept (verified): bias folded into GEMM (x k=28,29 slots=1.0, Wx frag
// carries hi/lo two-f16 bias split on quad==3, acc init=ZERO via MFMA
// D!=C), linear staging (re-derived for 256 thr: slot=(e>>1)*512+
// (e&1)*256+tid, goff=Gbase+(e>>1)*12544+(e&1)*16), fp16 datapath,
// per-lane c/h update, early global x loads / late LDS writes, W/bias
// pre-scaled {-L2E, 2L2E, -L2E, -L2E}, c in 2*L2E units, one barrier
// per step via h double-buffer, HSTRIDE=136 conflict-free rows.

typedef _Float16 f16x8 __attribute__((ext_vector_type(8)));
typedef float f32x4 __attribute__((ext_vector_type(4)));

#define HSTRIDE 136    // f16 elems; 272B row = 17*16B (b128-aligned rows)
#define L2E 1.44269504f

__global__ __launch_bounds__(256, 2)
void lstm_r20(const float* __restrict__ x,      // [B][28][28]
              const float* __restrict__ W,      // [156][512]
              const float* __restrict__ b,      // [512]
              const float* __restrict__ Wfc,    // [128][10]
              const float* __restrict__ bfc,    // [10]
              float* __restrict__ out)          // [B][10]
{
    __shared__ __align__(16) _Float16 h_s[2][64 * HSTRIDE];   // 34816 B
    __shared__ __align__(16) _Float16 xs[2][4 * 512];         //  8192 B
    __shared__ __align__(16) _Float16 wx_s[4][8][64][8];      // 32768 B
    // total 75776 B -> exactly 2 blocks/CU, independent barriers

    const int tid  = threadIdx.x;                // 0..255
    const int wave = tid >> 6;                   // 0..3
    const int lane = tid & 63;
    const int m16  = lane & 15;
    const int quad = lane >> 4;
    const int rbase = blockIdx.x * 64;

    // ---- zero h buf0; xs: k=28,29 slots = 1.0 (bias lanes), rest 0 ----
    for (int i = tid; i < 64 * HSTRIDE; i += 256) h_s[0][i] = (_Float16)0.0f;
    for (int i = tid; i < 2 * 4 * 512; i += 256) {
        const int q = i & 511;          // position within 512-elem chunk
        const bool bslot = ((q >> 7) == 3) && (((q & 7) == 4) || ((q & 7) == 5));
        ((_Float16*)xs)[i] = bslot ? (_Float16)1.0f : (_Float16)0.0f;
    }

    // ---- W fragments (fp16, pre-scaled); wave owns cols [wave*32, +32)
    // col-tile ct = g*2+half -> gate g, cols wave*32 + half*16 + m16.
    f16x8 Wh[4][8];
    #pragma unroll
    for (int ct = 0; ct < 8; ct++) {
        const int g = ct >> 1, half = ct & 1;
        const int col = g * 128 + wave * 32 + half * 16 + m16;
        const float sc = (g == 1) ? 2.0f * L2E : -L2E;
        f16x8 w8;
        #pragma unroll
        for (int j = 0; j < 8; j++) {
            const int kk = quad * 8 + j;
            w8[j] = (kk < 28) ? (_Float16)(sc * W[kk * 512 + col]) : (_Float16)0.0f;
        }
        if (quad == 3) {
            // kk==28/29: two-f16 hi/lo split of pre-scaled bias (FORGET folded)
            const float bv = sc * (b[col] + (g == 2 ? 1.0f : 0.0f));
            const _Float16 hi = (_Float16)bv;
            w8[4] = hi;
            w8[5] = (_Float16)(bv - (float)hi);
        }
        *(f16x8*)&wx_s[wave][ct][lane][0] = w8;
        #pragma unroll
        for (int ks = 0; ks < 4; ks++) {
            f16x8 h8;
            #pragma unroll
            for (int j = 0; j < 8; j++)
                h8[j] = (_Float16)(sc * W[(28 + ks * 32 + quad * 8 + j) * 512 + col]);
            Wh[ks][ct] = h8;
        }
    }

    // barrier: zero/bias init + wx_s writes complete before t=0 staging
    __syncthreads();

    // ---- x staging (256 thr): slot(e) = (e>>1)*512 + (e&1)*256 + tid ----
    // decode: row16=(tid>>3)&15, skE=((tid>>7)&1)*8+(tid&7) (even-e k),
    // odd-e k = skE+16 (valid iff skE<12). global = Gbase + (e>>1)*12544
    // + (e&1)*16; chunk/bias slots k>=28 never rewritten.
    const int row16 = (tid >> 3) & 15;
    const int skE   = ((tid >> 7) & 1) * 8 + (tid & 7);
    const bool vodd = (skE < 12);
    const int Gbase = (rbase + row16) * 784 + skE;   // < 25.7M, fits int

    // stage x for t=0
    #pragma unroll
    for (int e = 0; e < 8; e++)
        if (!(e & 1) || vodd)
            xs[0][(e >> 1) * 512 + (e & 1) * 256 + tid] =
                (_Float16)x[Gbase + (e >> 1) * 12544 + (e & 1) * 16];
    __syncthreads();

    float creg[32];
    #pragma unroll
    for (int i = 0; i < 32; i++) creg[i] = 0.0f;

    const int foff = quad * 128 + m16 * 8;   // A-frag offset inside a chunk
    const f32x4 ZERO = (f32x4){0.0f, 0.0f, 0.0f, 0.0f};

    int buf = 0;
    for (int t = 0; t < 28; t++) {
        const int nb = buf ^ 1;

        // ---- EARLY: issue global loads for t+1 (wait lands at step end) ----
        float xv[8];
        if (t < 27) {
            const float* xt = x + (t + 1) * 28;
            #pragma unroll
            for (int e = 0; e < 8; e++)
                if (!(e & 1) || vodd)
                    xv[e] = xt[Gbase + (e >> 1) * 12544 + (e & 1) * 16];
        }

        // ---- 4 row-tiles x 8 col-tiles: MFMA chain then activation ----
        #pragma unroll
        for (int mt = 0; mt < 4; mt++) {
            f32x4 acc[8];
            f16x8 ax = *(const f16x8*)(&xs[buf][mt * 512 + foff]);
            #pragma unroll
            for (int ct = 0; ct < 8; ct++) {
                f16x8 wx = *(const f16x8*)(&wx_s[wave][ct][lane][0]);
                acc[ct] = __builtin_amdgcn_mfma_f32_16x16x32_f16(ax, wx, ZERO, 0, 0, 0);
            }
            #pragma unroll
            for (int ks = 0; ks < 4; ks++) {
                f16x8 ah = *(const f16x8*)(&h_s[buf][(mt * 16 + m16) * HSTRIDE + ks * 32 + quad * 8]);
                #pragma unroll
                for (int ct = 0; ct < 8; ct++)
                    acc[ct] = __builtin_amdgcn_mfma_f32_16x16x32_f16(ah, Wh[ks][ct], acc[ct], 0, 0, 0);
            }

            // activation: 8 cells/lane (2 halves x 4 rows); gates at
            // acc[half], acc[2+half], acc[4+half], acc[6+half]
            #pragma unroll
            for (int half = 0; half < 2; half++)
                #pragma unroll
                for (int r = 0; r < 4; r++) {
                    float ei  = __builtin_amdgcn_exp2f(acc[0 + half][r]);   // e^-i
                    float e2j = __builtin_amdgcn_exp2f(acc[2 + half][r]);   // e^2j
                    float ef  = __builtin_amdgcn_exp2f(acc[4 + half][r]);   // e^-(f+1)
                    float eo  = __builtin_amdgcn_exp2f(acc[6 + half][r]);   // e^-o
                    float A   = 1.0f + ei;
                    float Bv  = e2j + 1.0f;
                    float C   = 1.0f + ef;
                    float AB  = A * Bv;
                    float rP  = __builtin_amdgcn_rcpf(AB * C);
                    float num = __builtin_fmaf(e2j, 2.0f * L2E, -2.0f * L2E);
                    const int ci = mt * 8 + half * 4 + r;
                    float cn  = __builtin_fmaf(creg[ci], AB * rP, num * (C * rP));
                    creg[ci] = cn;
                    float e2c = __builtin_amdgcn_exp2f(cn);                 // e^2c
                    float rQ  = __builtin_amdgcn_rcpf((e2c + 1.0f) * (1.0f + eo));
                    float hv  = (e2c - 1.0f) * rQ;
                    h_s[nb][(mt * 16 + quad * 4 + r) * HSTRIDE + wave * 32 + half * 16 + m16] = (_Float16)hv;
                }
        }

        // ---- LATE: stage x(t+1) to LDS (vmcnt satisfied long ago) ----
        if (t < 27) {
            #pragma unroll
            for (int e = 0; e < 8; e++)
                if (!(e & 1) || vodd)
                    xs[nb][(e >> 1) * 512 + (e & 1) * 256 + tid] = (_Float16)xv[e];
        }
        __syncthreads();
        buf = nb;
    }

    // ---- FC epilogue: logits = h @ Wfc + bfc (640 outputs) ----
    for (int i = tid; i < 640; i += 256) {
        const int row = i / 10, lab = i % 10;
        float acc = bfc[lab];
        #pragma unroll 8
        for (int k = 0; k < 128; k++)
            acc += (float)h_s[buf][row * HSTRIDE + k] * Wfc[k * 10 + lab];
        out[(size_t)(rbase + row) * 10 + lab] = acc;
    }
}

extern "C" void kernel_launch(void* const* d_in, const int* in_sizes, int n_in,
                              void* d_out, int out_size, void* d_ws, size_t ws_size,
                              hipStream_t stream) {
    const float* x   = (const float*)d_in[0];
    const float* W   = (const float*)d_in[1];
    const float* b   = (const float*)d_in[2];
    const float* Wfc = (const float*)d_in[3];
    const float* bfc = (const float*)d_in[4];
    float* out = (float*)d_out;

    const int B = in_sizes[0] / (28 * 28);   // 32768
    const int blocks = B / 64;               // 512 = two per CU
    lstm_r20<<<blocks, 256, 0, stream>>>(x, W, b, Wfc, bfc, out);
}